// Round 2
// baseline (40370.007 us; speedup 1.0000x reference)
//
#include <hip/hip_runtime.h>
#include <hip/hip_cooperative_groups.h>
#include <cstdint>
#include <cstddef>

namespace cg = cooperative_groups;

static constexpr int BS  = 128;
static constexpr int RAL = 1024;
static constexpr int LAL = 256;
static constexpr int CS  = 256;
static constexpr int VOC = 34;
static constexpr int HFS = 512;
static constexpr int EMB = 256;

static constexpr int NSPLIT = 2;
static constexpr int RSPL   = RAL / NSPLIT;   // max rows per split block

typedef float  f32x4  __attribute__((ext_vector_type(4)));
typedef short  bf16x8 __attribute__((ext_vector_type(8)));

static __device__ __forceinline__ float bflo(unsigned int u) {
    return __builtin_bit_cast(float, u << 16);
}
static __device__ __forceinline__ float bfhi(unsigned int u) {
    return __builtin_bit_cast(float, u & 0xffff0000u);
}
static __device__ __forceinline__ unsigned short f2bf(float f) {
    unsigned int x = __builtin_bit_cast(unsigned int, f);
    x = (x + 0x7fffu + ((x >> 16) & 1u)) >> 16;   // RNE
    return (unsigned short)x;
}
static __device__ __forceinline__ float sigf(float x)   { return 1.0f / (1.0f + __expf(-x)); }
static __device__ __forceinline__ float tanhf_(float x) { return 1.0f - 2.0f / (__expf(2.0f * x) + 1.0f); }

// ---------------- fp32 -> bf16 conversion (once per launch) ----------------
__global__ void cvt4_kernel(const float4* __restrict__ in, ushort4* __restrict__ out, int n4) {
    int i  = blockIdx.x * blockDim.x + threadIdx.x;
    int st = gridDim.x * blockDim.x;
    for (; i < n4; i += st) {
        float4 v = in[i];
        ushort4 o;
        o.x = f2bf(v.x); o.y = f2bf(v.y); o.z = f2bf(v.z); o.w = f2bf(v.w);
        out[i] = o;
    }
}

// ---------------- valid-length precompute (mask is a prefix mask) ----------------
__global__ __launch_bounds__(256) void len_kernel(const float* __restrict__ mask, int* __restrict__ Llen) {
    __shared__ int red[256];
    const int b = blockIdx.x, tid = threadIdx.x;
    int c = 0;
    for (int r = tid; r < RAL; r += 256) c += (mask[b * RAL + r] != 0.0f) ? 1 : 0;
    red[tid] = c;
    __syncthreads();
    for (int s = 128; s > 0; s >>= 1) {
        if (tid < s) red[tid] += red[tid + s];
        __syncthreads();
    }
    if (tid == 0) Llen[b] = red[0];
}

// ---------------- persistent-kernel shared memory overlays ----------------
struct SmLstm { float zp[7][4][64][4]; };          // 28672 B
struct SmAttn {
    float hb_l[HFS];       // 2048
    float q_lds[CS];       // 1024
    float e_lds[RSPL];     // 2048
    float ctxp[8][CS];     // 8192
    float red[16];         //   64
};
struct SmComb {
    float xcat[HFS + CS];  // 3072
    float wsc[NSPLIT];
};
static constexpr size_t SMSZ =
    sizeof(SmLstm) > sizeof(SmAttn)
        ? (sizeof(SmLstm) > sizeof(SmComb) ? sizeof(SmLstm) : sizeof(SmComb))
        : (sizeof(SmAttn) > sizeof(SmComb) ? sizeof(SmAttn) : sizeof(SmComb));

struct PParams {
    const void* keyp; const void* valp;
    const int* Llen; const int* y;
    const unsigned short* embb;
    const unsigned short* WihA; const unsigned short* WhhA;
    const float* bihA; const float* bhhA;
    const unsigned short* WihB; const unsigned short* WhhB;
    const float* bihB; const float* bhhB;
    const unsigned short* Wqb; const float* bq;
    const float* Wc; const float* bc;
    unsigned short* ha; unsigned short* hbuf;
    float* ca; float* cbuf;
    unsigned short* ctxbf;
    float* attM; float* attS; float* attC;
    float* outp;
};

// ---------------- LSTM phase: 8-wave K-split (128 wide each) ----------------
// block blk = (jslice = blk&31, bgroup = blk>>5); 512 threads.
// K layout [x(0:512) | h(0:512)]; seg = wv>>1 picks quarter, sub = wv&1 picks 128-half.
static __device__ __forceinline__ void lstm_phase(
    int blk, int tid,
    const unsigned short* p0, int s0,   // x[0:256]  (emb gather for LSTM A)
    const unsigned short* p1, int s1,   // x[256:512]
    const unsigned short* p2, int s2,   // h[0:256]
    const unsigned short* p3, int s3,   // h[256:512]
    const int* yidx, int t,
    const unsigned short* Wih, const unsigned short* Whh,
    const float* bih, const float* bhh,
    float* cst, unsigned short* hout,
    SmLstm* sm)
{
    const int lane = tid & 63;
    const int wv   = tid >> 6;      // 0..7
    const int seg  = wv >> 1;       // 0..3
    const int sub  = wv & 1;
    const int quad = lane >> 4;
    const int l16  = lane & 15;
    const int jsl  = blk & 31;
    const int bgr  = blk >> 5;
    const int j    = jsl * 16 + l16;
    const int mrow = bgr * 16 + l16;

    const unsigned short* base;
    int stride;
    if      (seg == 0) { base = p0; stride = s0; }
    else if (seg == 1) { base = p1; stride = s1; }
    else if (seg == 2) { base = p2; stride = s2; }
    else               { base = p3; stride = s3; }

    long rbase;
    if (seg == 0 && yidx) rbase = (long)yidx[mrow * LAL + t] * stride;  // embedding gather
    else                  rbase = (long)mrow * stride;

    const unsigned short* pa = base + rbase + sub * 128 + quad * 8;
    const unsigned short* wb = ((seg < 2) ? Wih : Whh) + (seg & 1) * 256 + sub * 128 + quad * 8;

    const unsigned short* wg[4];
#pragma unroll
    for (int g = 0; g < 4; ++g) wg[g] = wb + (long)(g * HFS + j) * HFS;

    f32x4 acc[4];
#pragma unroll
    for (int g = 0; g < 4; ++g) acc[g] = (f32x4)0.0f;

#pragma unroll
    for (int kc = 0; kc < 4; ++kc) {
        bf16x8 a  = *(const bf16x8*)(pa + kc * 32);
        bf16x8 b0 = *(const bf16x8*)(wg[0] + kc * 32);
        bf16x8 b1 = *(const bf16x8*)(wg[1] + kc * 32);
        bf16x8 b2 = *(const bf16x8*)(wg[2] + kc * 32);
        bf16x8 b3 = *(const bf16x8*)(wg[3] + kc * 32);
        acc[0] = __builtin_amdgcn_mfma_f32_16x16x32_bf16(a, b0, acc[0], 0, 0, 0);
        acc[1] = __builtin_amdgcn_mfma_f32_16x16x32_bf16(a, b1, acc[1], 0, 0, 0);
        acc[2] = __builtin_amdgcn_mfma_f32_16x16x32_bf16(a, b2, acc[2], 0, 0, 0);
        acc[3] = __builtin_amdgcn_mfma_f32_16x16x32_bf16(a, b3, acc[3], 0, 0, 0);
    }

    if (wv != 0) {
#pragma unroll
        for (int g = 0; g < 4; ++g)
            *(f32x4*)&sm->zp[wv - 1][g][lane][0] = acc[g];
    }
    __syncthreads();
    if (wv == 0) {
#pragma unroll
        for (int g = 0; g < 4; ++g) {
#pragma unroll
            for (int w = 0; w < 7; ++w)
                acc[g] += *(const f32x4*)&sm->zp[w][g][lane][0];
        }
        const float bI = bih[j]           + bhh[j];
        const float bF = bih[HFS + j]     + bhh[HFS + j];
        const float bG = bih[2 * HFS + j] + bhh[2 * HFS + j];
        const float bO = bih[3 * HFS + j] + bhh[3 * HFS + j];
#pragma unroll
        for (int r = 0; r < 4; ++r) {
            int m   = bgr * 16 + quad * 4 + r;  // C/D row = batch
            int idx = m * HFS + j;
            float iv = sigf(acc[0][r] + bI);
            float fv = sigf(acc[1][r] + bF);
            float gv = tanhf_(acc[2][r] + bG);
            float ov = sigf(acc[3][r] + bO);
            float cn = fv * cst[idx] + iv * gv;
            cst[idx] = cn;
            hout[idx] = f2bf(ov * tanhf_(cn));
        }
    }
}

// ---------------- attention partial phase (block = (b, sp), 512 threads) ----------------
template <bool KVBF>
static __device__ __forceinline__ void attn_phase(
    int blk, int tid,
    const void* keyp, const void* valp,
    const int* __restrict__ Llen,
    const unsigned short* __restrict__ hbv,
    const unsigned short* __restrict__ Wqb, const float* __restrict__ bq,
    float* __restrict__ attM, float* __restrict__ attS, float* __restrict__ attC,
    SmAttn* sm)
{
    const int b     = blk >> 1;
    const int sp    = blk & 1;
    const int L     = Llen[b];
    const int rhalf = (L + 1) >> 1;               // balanced split boundary
    const int rbase = sp * rhalf;
    int nv = L - rbase;
    if (nv > rhalf) nv = rhalf;

    if (nv <= 0) {
        if (tid < CS) attC[((long)b * NSPLIT + sp) * CS + tid] = 0.0f;
        if (tid == 0) { attM[b * NSPLIT + sp] = -1e30f; attS[b * NSPLIT + sp] = 0.0f; }
        return;
    }

    sm->hb_l[tid] = bflo((unsigned int)hbv[b * HFS + tid]);   // tid < 512 == HFS
    __syncthreads();

    // query: 2 threads per output col, each covers K=256
    {
        const int c  = tid >> 1;
        const int jj = tid & 1;
        const unsigned short* wr = Wqb + (long)c * HFS + jj * 256;
        const float* xr = &sm->hb_l[jj * 256];
        float qa = 0.0f;
#pragma unroll 8
        for (int k = 0; k < 256; k += 8) {
            uint4 u = *(const uint4*)(wr + k);
            float4 h0 = *(const float4*)(xr + k);
            float4 h1 = *(const float4*)(xr + k + 4);
            qa += bflo(u.x) * h0.x + bfhi(u.x) * h0.y
                + bflo(u.y) * h0.z + bfhi(u.y) * h0.w
                + bflo(u.z) * h1.x + bfhi(u.z) * h1.y
                + bflo(u.w) * h1.z + bfhi(u.w) * h1.w;
        }
        qa += __shfl_xor(qa, 1);
        if (jj == 0) sm->q_lds[c] = qa + bq[c];
    }
    __syncthreads();

    // energy: 8 threads per row (32 contiguous channels each), 64 rows per pass
    {
        const int jj   = tid & 7;
        const int rloc = tid >> 3;      // 0..63
        for (int r0 = 0; r0 < nv; r0 += 64) {
            const int r = r0 + rloc;
            float acc = 0.0f;
            if (r < nv) {
                if (KVBF) {
                    const unsigned short* kp = (const unsigned short*)keyp
                        + ((long)b * RAL + rbase + r) * CS + jj * 32;
#pragma unroll
                    for (int i = 0; i < 4; ++i) {
                        uint4 u = *(const uint4*)(kp + i * 8);
                        const float* qp = &sm->q_lds[jj * 32 + i * 8];
                        float4 qa  = *(const float4*)qp;
                        float4 qb2 = *(const float4*)(qp + 4);
                        acc += bflo(u.x) * qa.x  + bfhi(u.x) * qa.y
                             + bflo(u.y) * qa.z  + bfhi(u.y) * qa.w
                             + bflo(u.z) * qb2.x + bfhi(u.z) * qb2.y
                             + bflo(u.w) * qb2.z + bfhi(u.w) * qb2.w;
                    }
                } else {
                    const float* kp = (const float*)keyp
                        + ((long)b * RAL + rbase + r) * CS + jj * 32;
#pragma unroll
                    for (int i = 0; i < 8; ++i) {
                        float4 kv = *(const float4*)(kp + i * 4);
                        float4 qa = *(const float4*)&sm->q_lds[jj * 32 + i * 4];
                        acc += kv.x * qa.x + kv.y * qa.y + kv.z * qa.z + kv.w * qa.w;
                    }
                }
            }
            acc += __shfl_xor(acc, 1);
            acc += __shfl_xor(acc, 2);
            acc += __shfl_xor(acc, 4);
            if (jj == 0 && r < nv) sm->e_lds[r] = acc;
        }
    }
    __syncthreads();

    // local softmax stats (nv <= 512, one row per thread)
    float pm = (tid < nv) ? sm->e_lds[tid] : -1e30f;
#pragma unroll
    for (int s = 32; s > 0; s >>= 1) pm = fmaxf(pm, __shfl_xor(pm, s));
    if ((tid & 63) == 0) sm->red[tid >> 6] = pm;
    __syncthreads();
    float M = sm->red[0];
#pragma unroll
    for (int i = 1; i < 8; ++i) M = fmaxf(M, sm->red[i]);

    float ps = 0.0f;
    if (tid < nv) { float v = __expf(sm->e_lds[tid] - M); sm->e_lds[tid] = v; ps = v; }
#pragma unroll
    for (int s = 32; s > 0; s >>= 1) ps += __shfl_xor(ps, s);
    if ((tid & 63) == 0) sm->red[8 + (tid >> 6)] = ps;
    __syncthreads();
    float S = 0.0f;
#pragma unroll
    for (int i = 0; i < 8; ++i) S += sm->red[8 + i];

    if (tid == 0) { attM[b * NSPLIT + sp] = M; attS[b * NSPLIT + sp] = S; }

    // partial context (unnormalized): 8 waves, rows == wv (mod 8), lane owns 4 channels
    {
        const int wv = tid >> 6;
        const int c4 = (tid & 63) * 4;
        float a0 = 0.f, a1 = 0.f, a2 = 0.f, a3 = 0.f;
        if (KVBF) {
            const unsigned short* vb = (const unsigned short*)valp
                + ((long)b * RAL + rbase) * CS + c4;
            int r = wv;
            for (; r + 24 < nv; r += 32) {
                uint2 u0 = *(const uint2*)(vb + (long)(r)      * CS);
                uint2 u1 = *(const uint2*)(vb + (long)(r + 8)  * CS);
                uint2 u2 = *(const uint2*)(vb + (long)(r + 16) * CS);
                uint2 u3 = *(const uint2*)(vb + (long)(r + 24) * CS);
                float w0 = sm->e_lds[r],      w1 = sm->e_lds[r + 8];
                float w2 = sm->e_lds[r + 16], w3 = sm->e_lds[r + 24];
                a0 += w0 * bflo(u0.x) + w1 * bflo(u1.x) + w2 * bflo(u2.x) + w3 * bflo(u3.x);
                a1 += w0 * bfhi(u0.x) + w1 * bfhi(u1.x) + w2 * bfhi(u2.x) + w3 * bfhi(u3.x);
                a2 += w0 * bflo(u0.y) + w1 * bflo(u1.y) + w2 * bflo(u2.y) + w3 * bflo(u3.y);
                a3 += w0 * bfhi(u0.y) + w1 * bfhi(u1.y) + w2 * bfhi(u2.y) + w3 * bfhi(u3.y);
            }
            for (; r < nv; r += 8) {
                uint2 u = *(const uint2*)(vb + (long)r * CS);
                float w = sm->e_lds[r];
                a0 += w * bflo(u.x); a1 += w * bfhi(u.x);
                a2 += w * bflo(u.y); a3 += w * bfhi(u.y);
            }
        } else {
            const float* vb = (const float*)valp + ((long)b * RAL + rbase) * CS + c4;
            int r = wv;
            for (; r + 24 < nv; r += 32) {
                float4 v0 = *(const float4*)(vb + (long)(r)      * CS);
                float4 v1 = *(const float4*)(vb + (long)(r + 8)  * CS);
                float4 v2 = *(const float4*)(vb + (long)(r + 16) * CS);
                float4 v3 = *(const float4*)(vb + (long)(r + 24) * CS);
                float w0 = sm->e_lds[r],      w1 = sm->e_lds[r + 8];
                float w2 = sm->e_lds[r + 16], w3 = sm->e_lds[r + 24];
                a0 += w0 * v0.x + w1 * v1.x + w2 * v2.x + w3 * v3.x;
                a1 += w0 * v0.y + w1 * v1.y + w2 * v2.y + w3 * v3.y;
                a2 += w0 * v0.z + w1 * v1.z + w2 * v2.z + w3 * v3.z;
                a3 += w0 * v0.w + w1 * v1.w + w2 * v2.w + w3 * v3.w;
            }
            for (; r < nv; r += 8) {
                float4 v = *(const float4*)(vb + (long)r * CS);
                float w = sm->e_lds[r];
                a0 += w * v.x; a1 += w * v.y; a2 += w * v.z; a3 += w * v.w;
            }
        }
        float4 out4 = {a0, a1, a2, a3};
        *(float4*)&sm->ctxp[tid >> 6][c4] = out4;
    }
    __syncthreads();

    if (tid < CS) {
        float cv = 0.0f;
#pragma unroll
        for (int w = 0; w < 8; ++w) cv += sm->ctxp[w][tid];
        attC[((long)b * NSPLIT + sp) * CS + tid] = cv;   // unnormalized
    }
}

// ---------------- combine + logits phase (blocks 0..127, 512 threads) ----------------
static __device__ __forceinline__ void comb_phase(
    int b, int tid,
    const float* __restrict__ attM, const float* __restrict__ attS,
    const float* __restrict__ attC,
    const unsigned short* __restrict__ hbv,
    const float* __restrict__ Wc, const float* __restrict__ bc,
    unsigned short* __restrict__ ctxbf,
    float* __restrict__ outp, int t,
    SmComb* sm)
{
    if (tid == 0) {
        float M = attM[b * NSPLIT];
#pragma unroll
        for (int s = 1; s < NSPLIT; ++s) M = fmaxf(M, attM[b * NSPLIT + s]);
        float S = 0.0f;
        float w[NSPLIT];
#pragma unroll
        for (int s = 0; s < NSPLIT; ++s) {
            w[s] = __expf(attM[b * NSPLIT + s] - M);
            S += w[s] * attS[b * NSPLIT + s];
        }
        const float invS = 1.0f / S;
#pragma unroll
        for (int s = 0; s < NSPLIT; ++s) sm->wsc[s] = w[s] * invS;
    }
    sm->xcat[tid] = bflo((unsigned int)hbv[b * HFS + tid]);   // tid < 512 == HFS
    __syncthreads();

    if (tid < CS) {
        float cv = 0.0f;
#pragma unroll
        for (int s = 0; s < NSPLIT; ++s)
            cv += sm->wsc[s] * attC[((long)b * NSPLIT + s) * CS + tid];
        sm->xcat[HFS + tid] = cv;
        ctxbf[b * CS + tid] = f2bf(cv);
    }
    __syncthreads();

    // logits: 8 threads per vocab entry, float4 loads
    if (tid < VOC * 8) {
        const int v   = tid >> 3;
        const int jj2 = tid & 7;
        const float* wr = Wc + (long)v * (HFS + CS) + jj2 * 96;
        const float* xr = &sm->xcat[jj2 * 96];
        float part = 0.0f;
#pragma unroll
        for (int i = 0; i < 24; ++i) {
            float4 wv4 = *(const float4*)(wr + i * 4);
            float4 xv  = *(const float4*)(xr + i * 4);
            part += wv4.x * xv.x + wv4.y * xv.y + wv4.z * xv.z + wv4.w * xv.w;
        }
        part += __shfl_xor(part, 1);
        part += __shfl_xor(part, 2);
        part += __shfl_xor(part, 4);
        if (jj2 == 0)
            outp[((long)b * LAL + t) * VOC + v] = part + bc[v];
    }
}

// ---------------- the persistent kernel: all 256 timesteps, 4 grid syncs/step ----------------
template <bool KVBF>
__global__ __launch_bounds__(512, 2) void persist_kernel(PParams P)
{
    cg::grid_group grid = cg::this_grid();
    __shared__ __align__(16) unsigned char smraw[SMSZ];
    SmLstm* smL = (SmLstm*)smraw;
    SmAttn* smA = (SmAttn*)smraw;
    SmComb* smC = (SmComb*)smraw;

    const int blk = blockIdx.x;
    const int tid = threadIdx.x;

    for (int t = 0; t < LAL; ++t) {
        unsigned short* haIn  = P.ha   + (t & 1) * (BS * HFS);
        unsigned short* haOut = P.ha   + ((t + 1) & 1) * (BS * HFS);
        unsigned short* hbIn  = P.hbuf + (t & 1) * (BS * HFS);
        unsigned short* hbOut = P.hbuf + ((t + 1) & 1) * (BS * HFS);

        // LSTM A: x = [emb[y_t] | ctx], h = haIn
        lstm_phase(blk, tid,
                   P.embb, EMB, P.ctxbf, CS, haIn, HFS, haIn + 256, HFS,
                   P.y, t, P.WihA, P.WhhA, P.bihA, P.bhhA, P.ca, haOut, smL);
        grid.sync();

        // LSTM B: x = haOut, h = hbIn
        lstm_phase(blk, tid,
                   haOut, HFS, haOut + 256, HFS, hbIn, HFS, hbIn + 256, HFS,
                   nullptr, t, P.WihB, P.WhhB, P.bihB, P.bhhB, P.cbuf, hbOut, smL);
        grid.sync();

        // attention partials (block = (b, split))
        attn_phase<KVBF>(blk, tid, P.keyp, P.valp, P.Llen, hbOut,
                         P.Wqb, P.bq, P.attM, P.attS, P.attC, smA);
        grid.sync();

        // combine + logits (blocks 0..127)
        if (blk < BS)
            comb_phase(blk, tid, P.attM, P.attS, P.attC, hbOut,
                       P.Wc, P.bc, P.ctxbf, P.outp, t, smC);
        grid.sync();
    }
}

// ---------------- host ----------------
extern "C" void kernel_launch(void* const* d_in, const int* in_sizes, int n_in,
                              void* d_out, int out_size, void* d_ws, size_t ws_size,
                              hipStream_t stream)
{
    (void)in_sizes; (void)n_in; (void)out_size;
    const float* keyf  = (const float*)d_in[0];
    const float* valf  = (const float*)d_in[1];
    const float* mask  = (const float*)d_in[2];
    const float* embf  = (const float*)d_in[3];
    const float* WihAf = (const float*)d_in[4];
    const float* WhhAf = (const float*)d_in[5];
    const float* bihA  = (const float*)d_in[6];
    const float* bhhA  = (const float*)d_in[7];
    const float* WihBf = (const float*)d_in[8];
    const float* WhhBf = (const float*)d_in[9];
    const float* bihB  = (const float*)d_in[10];
    const float* bhhB  = (const float*)d_in[11];
    const float* Wqf   = (const float*)d_in[12];
    const float* bq    = (const float*)d_in[13];
    const float* Wc    = (const float*)d_in[14];
    const float* bc    = (const float*)d_in[15];
    const int*   y     = (const int*)d_in[16];
    float* outp = (float*)d_out;

    size_t off = 0;
    auto take = [&](size_t bytes) -> void* {
        void* p = (char*)d_ws + off;
        off += (bytes + 255) & ~(size_t)255;
        return p;
    };

    // zero-initialized state block
    unsigned short* ha    = (unsigned short*)take((size_t)2 * BS * HFS * 2); // double-buffered
    unsigned short* hbuf  = (unsigned short*)take((size_t)2 * BS * HFS * 2); // double-buffered
    float*          ca    = (float*)take((size_t)BS * HFS * 4);
    float*          cbuf  = (float*)take((size_t)BS * HFS * 4);
    unsigned short* ctxbf = (unsigned short*)take((size_t)BS * CS * 2);
    size_t stateBytes = off;

    int*            Llen  = (int*)take((size_t)BS * 4);
    unsigned short* embb  = (unsigned short*)take((size_t)VOC * EMB * 2);
    unsigned short* WihAb = (unsigned short*)take((size_t)4 * HFS * HFS * 2);
    unsigned short* WhhAb = (unsigned short*)take((size_t)4 * HFS * HFS * 2);
    unsigned short* WihBb = (unsigned short*)take((size_t)4 * HFS * HFS * 2);
    unsigned short* WhhBb = (unsigned short*)take((size_t)4 * HFS * HFS * 2);
    unsigned short* Wqb   = (unsigned short*)take((size_t)CS * HFS * 2);

    // attention split partials
    float* attM = (float*)take((size_t)BS * NSPLIT * 4);
    float* attS = (float*)take((size_t)BS * NSPLIT * 4);
    float* attC = (float*)take((size_t)BS * NSPLIT * CS * 4);

    // --- KV bf16 tiers ---
    const size_t kvBytes = (size_t)BS * RAL * CS * 2;  // 67 MB each
    unsigned short* keyb = nullptr;
    unsigned short* valb = nullptr;
    bool kvbf = false;
    bool keyInVal = false;
    if (off + 2 * (kvBytes + 256) <= ws_size) {
        keyb = (unsigned short*)take(kvBytes);
        valb = (unsigned short*)take(kvBytes);
        kvbf = true;
    } else if (off + kvBytes + 256 <= ws_size) {
        valb = (unsigned short*)take(kvBytes);
        keyb = (unsigned short*)d_in[1];
        kvbf = true;
        keyInVal = true;
    }

    hipMemsetAsync(d_ws, 0, stateBytes, stream);
    len_kernel<<<dim3(BS), dim3(256), 0, stream>>>(mask, Llen);

    auto cvt = [&](const float* src, unsigned short* dst, long n) {
        int n4 = (int)(n / 4);
        int blocks = (n4 + 255) / 256;
        if (blocks > 8192) blocks = 8192;
        cvt4_kernel<<<dim3(blocks), dim3(256), 0, stream>>>((const float4*)src, (ushort4*)dst, n4);
    };
    cvt(embf,  embb,  (long)VOC * EMB);
    cvt(WihAf, WihAb, (long)4 * HFS * HFS);
    cvt(WhhAf, WhhAb, (long)4 * HFS * HFS);
    cvt(WihBf, WihBb, (long)4 * HFS * HFS);
    cvt(WhhBf, WhhBb, (long)4 * HFS * HFS);
    cvt(Wqf,   Wqb,   (long)CS * HFS);
    if (kvbf) {
        if (keyInVal) {
            cvt(valf, valb, (long)BS * RAL * CS);   // must finish before key overwrites d_in[1]
            cvt(keyf, keyb, (long)BS * RAL * CS);
        } else {
            cvt(keyf, keyb, (long)BS * RAL * CS);
            cvt(valf, valb, (long)BS * RAL * CS);
        }
    }

    PParams prm;
    prm.keyp = kvbf ? (const void*)keyb : (const void*)keyf;
    prm.valp = kvbf ? (const void*)valb : (const void*)valf;
    prm.Llen = Llen; prm.y = y;
    prm.embb = embb;
    prm.WihA = WihAb; prm.WhhA = WhhAb; prm.bihA = bihA; prm.bhhA = bhhA;
    prm.WihB = WihBb; prm.WhhB = WhhBb; prm.bihB = bihB; prm.bhhB = bhhB;
    prm.Wqb = Wqb; prm.bq = bq; prm.Wc = Wc; prm.bc = bc;
    prm.ha = ha; prm.hbuf = hbuf; prm.ca = ca; prm.cbuf = cbuf;
    prm.ctxbf = ctxbf;
    prm.attM = attM; prm.attS = attS; prm.attC = attC;
    prm.outp = outp;

    void* kargs[] = { &prm };
    if (kvbf)
        hipLaunchCooperativeKernel(reinterpret_cast<void*>(&persist_kernel<true>),
                                   dim3(256), dim3(512), kargs, 0, stream);
    else
        hipLaunchCooperativeKernel(reinterpret_cast<void*>(&persist_kernel<false>),
                                   dim3(256), dim3(512), kargs, 0, stream);
}

// Round 3
// 13003.810 us; speedup vs baseline: 3.1045x; 3.1045x over previous
//
#include <hip/hip_runtime.h>
#include <cstdint>
#include <cstddef>

static constexpr int BS  = 128;
static constexpr int RAL = 1024;
static constexpr int LAL = 256;
static constexpr int CS  = 256;
static constexpr int VOC = 34;
static constexpr int HFS = 512;
static constexpr int EMB = 256;

static constexpr int NSPLIT = 2;
static constexpr int RSPL   = RAL / NSPLIT;   // max rows per split block
static constexpr int NBLK   = 256;

typedef float  f32x4  __attribute__((ext_vector_type(4)));
typedef short  bf16x8 __attribute__((ext_vector_type(8)));

#define SC_AGENT __HIP_MEMORY_SCOPE_AGENT

static __device__ __forceinline__ float bflo(unsigned int u) {
    return __builtin_bit_cast(float, u << 16);
}
static __device__ __forceinline__ float bfhi(unsigned int u) {
    return __builtin_bit_cast(float, u & 0xffff0000u);
}
static __device__ __forceinline__ unsigned short f2bf(float f) {
    unsigned int x = __builtin_bit_cast(unsigned int, f);
    x = (x + 0x7fffu + ((x >> 16) & 1u)) >> 16;   // RNE
    return (unsigned short)x;
}
static __device__ __forceinline__ float bcf(unsigned u) { return __builtin_bit_cast(float, u); }
static __device__ __forceinline__ unsigned fcb(float f) { return __builtin_bit_cast(unsigned, f); }
static __device__ __forceinline__ float sigf(float x)   { return 1.0f / (1.0f + __expf(-x)); }
static __device__ __forceinline__ float tanhf_(float x) { return 1.0f - 2.0f / (__expf(2.0f * x) + 1.0f); }

// ---- agent-scope (device-coherent) accessors: bypass non-coherent L1/L2 ----
static __device__ __forceinline__ unsigned ldu32(const void* p) {
    return __hip_atomic_load((const unsigned*)p, __ATOMIC_RELAXED, SC_AGENT);
}
static __device__ __forceinline__ unsigned long long ldu64(const void* p) {
    return __hip_atomic_load((const unsigned long long*)p, __ATOMIC_RELAXED, SC_AGENT);
}
static __device__ __forceinline__ void stu32(void* p, unsigned v) {
    __hip_atomic_store((unsigned*)p, v, __ATOMIC_RELAXED, SC_AGENT);
}
static __device__ __forceinline__ void stu64(void* p, unsigned long long v) {
    __hip_atomic_store((unsigned long long*)p, v, __ATOMIC_RELAXED, SC_AGENT);
}
static __device__ __forceinline__ bf16x8 ld_bf16x8_sys(const unsigned short* p) {
    union { unsigned long long q[2]; bf16x8 v; } u;
    u.q[0] = ldu64(p);
    u.q[1] = ldu64(p + 4);
    return u.v;
}
static __device__ __forceinline__ unsigned long long packbf4(float a, float b, float c, float d) {
    return (unsigned long long)f2bf(a)
         | ((unsigned long long)f2bf(b) << 16)
         | ((unsigned long long)f2bf(c) << 32)
         | ((unsigned long long)f2bf(d) << 48);
}

// ---------------- fp32 -> bf16 conversion (once per launch) ----------------
__global__ void cvt4_kernel(const float4* __restrict__ in, ushort4* __restrict__ out, int n4) {
    int i  = blockIdx.x * blockDim.x + threadIdx.x;
    int st = gridDim.x * blockDim.x;
    for (; i < n4; i += st) {
        float4 v = in[i];
        ushort4 o;
        o.x = f2bf(v.x); o.y = f2bf(v.y); o.z = f2bf(v.z); o.w = f2bf(v.w);
        out[i] = o;
    }
}

// ---------------- valid-length precompute + attS init ----------------
__global__ __launch_bounds__(256) void len_kernel(const float* __restrict__ mask,
                                                  int* __restrict__ Llen,
                                                  float* __restrict__ attS) {
    __shared__ int red[256];
    const int b = blockIdx.x, tid = threadIdx.x;
    int c = 0;
    for (int r = tid; r < RAL; r += 256) c += (mask[b * RAL + r] != 0.0f) ? 1 : 0;
    red[tid] = c;
    __syncthreads();
    for (int s = 128; s > 0; s >>= 1) {
        if (tid < s) red[tid] += red[tid + s];
        __syncthreads();
    }
    if (tid == 0) Llen[b] = red[0];
    if (tid < NSPLIT) attS[b * NSPLIT + tid] = 0.5f;   // with attM=0, attC=0 -> ctx=0 at t=0
}

// ---------------- shared-memory overlays ----------------
struct SmLstm {
    float zp[7][4][64][4];   // 28672 B
    float hT[16][17];        //  1088 B  (epilogue transpose for packed h stores)
};
struct SmAttn {
    float hb_l[HFS];       // 2048
    float q_lds[CS];       // 1024
    float e_lds[RSPL];     // 2048
    float ctxp[8][CS];     // 8192
    float red[16];
};
static constexpr size_t SMSZ = sizeof(SmLstm) > sizeof(SmAttn) ? sizeof(SmLstm) : sizeof(SmAttn);

struct PParams {
    const void* keyp; const void* valp;
    const int* Llen; const int* y;
    const unsigned short* embb;
    const unsigned short* WihA; const unsigned short* WhhA;
    const float* bihA; const float* bhhA;
    const unsigned short* WihB; const unsigned short* WhhB;
    const float* bihB; const float* bhhB;
    const unsigned short* Wqb; const float* bq;
    const float* Wc; const float* bc;
    unsigned short* ha; unsigned short* hbuf;
    float* ca; float* cbuf;
    float* attM; float* attS; float* attC;
    unsigned* grp; unsigned* root;
    float* outp;
};

// ---------------- hierarchical monotonic grid barrier (no cache maintenance) ----------------
static __device__ __forceinline__ void gbar(unsigned* grp, unsigned* root, int blk, int round) {
    // drain this wave's coherent stores to the coherence point
    asm volatile("s_waitcnt vmcnt(0) lgkmcnt(0)" ::: "memory");
    __syncthreads();                       // all waves of the block drained
    if (threadIdx.x == 0) {
        unsigned* g = grp + (blk >> 4) * 32;            // 16 groups, 128B-padded lines
        unsigned old = __hip_atomic_fetch_add(g, 1u, __ATOMIC_RELAXED, SC_AGENT);
        if (old == (unsigned)(round * 16 + 15))         // last of the group this round
            __hip_atomic_fetch_add(root, 1u, __ATOMIC_RELAXED, SC_AGENT);
        const unsigned tgt = (unsigned)((round + 1) * 16);
        while (__hip_atomic_load(root, __ATOMIC_RELAXED, SC_AGENT) < tgt)
            __builtin_amdgcn_s_sleep(8);
    }
    __syncthreads();
}

// ---------------- ctx merge: 8 bf16 elems from two unnormalized partials ----------------
static __device__ __forceinline__ bf16x8 ctx_merge8(const float* c0, const float* c1,
                                                    float w0, float w1) {
    union { unsigned short s[8]; bf16x8 v; } r;
#pragma unroll
    for (int g = 0; g < 4; ++g) {
        unsigned long long qa = ldu64(c0 + g * 2);
        unsigned long long qb = ldu64(c1 + g * 2);
        float ax = bcf((unsigned)qa), ay = bcf((unsigned)(qa >> 32));
        float bx = bcf((unsigned)qb), by = bcf((unsigned)(qb >> 32));
        r.s[g * 2 + 0] = f2bf(w0 * ax + w1 * bx);
        r.s[g * 2 + 1] = f2bf(w0 * ay + w1 * by);
    }
    return r.v;
}

// ---------------- LSTM phase: 8-wave K-split (128 wide each) ----------------
// ISA (LSTM A): x = [emb gather | inline ctx merge]; else x = haOut row (coherent).
template <bool ISA>
static __device__ __forceinline__ void lstm_phase(
    int blk, int tid,
    const unsigned short* xrow,            // !ISA: haOut base (stride HFS)
    const float* attM, const float* attS, const float* attC,   // ISA only
    const unsigned short* embb, const int* yidx, int t,        // ISA only
    const unsigned short* hIn,             // h-state base (stride HFS), coherent
    const unsigned short* Wih, const unsigned short* Whh,
    const float* bih, const float* bhh,
    float* cst, unsigned short* hout,
    SmLstm* sm)
{
    const int lane = tid & 63;
    const int wv   = tid >> 6;      // 0..7
    const int seg  = wv >> 1;       // 0..3
    const int sub  = wv & 1;
    const int quad = lane >> 4;
    const int l16  = lane & 15;
    const int jsl  = blk & 31;
    const int bgr  = blk >> 5;
    const int j    = jsl * 16 + l16;
    const int mrow = bgr * 16 + l16;
    const int off0 = sub * 128 + quad * 8;

    const unsigned short* arow = nullptr;
    const float* c0 = nullptr;
    float w0m = 0.0f, w1m = 0.0f;
    bool scA;
    if (seg >= 2) {            // h-state
        arow = hIn + (long)mrow * HFS + (seg & 1) * 256 + off0;
        scA = true;
    } else if (!ISA) {         // x = haOut row
        arow = xrow + (long)mrow * HFS + (seg & 1) * 256 + off0;
        scA = true;
    } else if (seg == 0) {     // emb gather (plain, read-only)
        arow = embb + (long)yidx[mrow * LAL + t] * EMB + off0;
        scA = false;
    } else {                   // ctx merge
        c0 = attC + (long)mrow * NSPLIT * CS + off0;
        float M0 = bcf(ldu32(attM + mrow * 2)),     M1 = bcf(ldu32(attM + mrow * 2 + 1));
        float S0 = bcf(ldu32(attS + mrow * 2)),     S1 = bcf(ldu32(attS + mrow * 2 + 1));
        float mm = fmaxf(M0, M1);
        float e0 = __expf(M0 - mm), e1 = __expf(M1 - mm);
        float inv = 1.0f / (e0 * S0 + e1 * S1);
        w0m = e0 * inv; w1m = e1 * inv;
        scA = false;
    }

    const unsigned short* wb = ((seg < 2) ? Wih : Whh) + (seg & 1) * 256 + off0;
    const unsigned short* wg[4];
#pragma unroll
    for (int g = 0; g < 4; ++g) wg[g] = wb + (long)(g * HFS + j) * HFS;

    f32x4 acc[4];
#pragma unroll
    for (int g = 0; g < 4; ++g) acc[g] = (f32x4)0.0f;

#pragma unroll
    for (int kc = 0; kc < 4; ++kc) {
        bf16x8 a;
        if (scA)                 a = ld_bf16x8_sys(arow + kc * 32);
        else if (!ISA || seg == 0) a = *(const bf16x8*)(arow + kc * 32);
        else                     a = ctx_merge8(c0 + kc * 32, c0 + CS + kc * 32, w0m, w1m);
        bf16x8 b0 = *(const bf16x8*)(wg[0] + kc * 32);
        bf16x8 b1 = *(const bf16x8*)(wg[1] + kc * 32);
        bf16x8 b2 = *(const bf16x8*)(wg[2] + kc * 32);
        bf16x8 b3 = *(const bf16x8*)(wg[3] + kc * 32);
        acc[0] = __builtin_amdgcn_mfma_f32_16x16x32_bf16(a, b0, acc[0], 0, 0, 0);
        acc[1] = __builtin_amdgcn_mfma_f32_16x16x32_bf16(a, b1, acc[1], 0, 0, 0);
        acc[2] = __builtin_amdgcn_mfma_f32_16x16x32_bf16(a, b2, acc[2], 0, 0, 0);
        acc[3] = __builtin_amdgcn_mfma_f32_16x16x32_bf16(a, b3, acc[3], 0, 0, 0);
    }

    if (wv != 0) {
#pragma unroll
        for (int g = 0; g < 4; ++g)
            *(f32x4*)&sm->zp[wv - 1][g][lane][0] = acc[g];
    }
    __syncthreads();
    if (wv == 0) {
#pragma unroll
        for (int g = 0; g < 4; ++g) {
#pragma unroll
            for (int w = 0; w < 7; ++w)
                acc[g] += *(const f32x4*)&sm->zp[w][g][lane][0];
        }
        const float bI = bih[j]           + bhh[j];
        const float bF = bih[HFS + j]     + bhh[HFS + j];
        const float bG = bih[2 * HFS + j] + bhh[2 * HFS + j];
        const float bO = bih[3 * HFS + j] + bhh[3 * HFS + j];
#pragma unroll
        for (int r = 0; r < 4; ++r) {
            int m   = bgr * 16 + quad * 4 + r;  // C/D row = batch
            int idx = m * HFS + j;
            float iv = sigf(acc[0][r] + bI);
            float fv = sigf(acc[1][r] + bF);
            float gv = tanhf_(acc[2][r] + bG);
            float ov = sigf(acc[3][r] + bO);
            float cn = fv * cst[idx] + iv * gv;
            cst[idx] = cn;
            sm->hT[quad * 4 + r][l16] = ov * tanhf_(cn);
        }
        // transpose & coherent-store packed h (4 bf16 per lane)
        float h0 = sm->hT[l16][quad * 4 + 0];
        float h1 = sm->hT[l16][quad * 4 + 1];
        float h2 = sm->hT[l16][quad * 4 + 2];
        float h3 = sm->hT[l16][quad * 4 + 3];
        stu64(hout + (long)(bgr * 16 + l16) * HFS + jsl * 16 + quad * 4,
              packbf4(h0, h1, h2, h3));
    }
}

// ---------------- attention partial phase (block = (b, sp), 512 threads) ----------------
template <bool KVBF>
static __device__ __forceinline__ void attn_phase(
    int blk, int tid,
    const void* keyp, const void* valp,
    const int* __restrict__ Llen,
    const unsigned short* __restrict__ hbv,
    const unsigned short* __restrict__ Wqb, const float* __restrict__ bq,
    float* __restrict__ attM, float* __restrict__ attS, float* __restrict__ attC,
    SmAttn* sm)
{
    const int b     = blk >> 1;
    const int sp    = blk & 1;
    const int L     = Llen[b];
    const int rhalf = (L + 1) >> 1;               // balanced split boundary
    const int rbase = sp * rhalf;
    int nv = L - rbase;
    if (nv > rhalf) nv = rhalf;

    if (nv <= 0) {
        if (tid < CS) stu32(attC + ((long)b * NSPLIT + sp) * CS + tid, fcb(0.0f));
        if (tid == 0) {
            stu32(attM + b * NSPLIT + sp, fcb(-1e30f));
            stu32(attS + b * NSPLIT + sp, fcb(0.0f));
        }
        return;
    }

    if (tid < 128) {   // coherent-load hb row, 4 bf16 per thread
        unsigned long long q = ldu64(hbv + (long)b * HFS + tid * 4);
        sm->hb_l[tid * 4 + 0] = bflo((unsigned)(q       ) & 0xffffu ? (unsigned)(q) & 0xffffu : 0u);
        sm->hb_l[tid * 4 + 0] = bflo((unsigned)(q        & 0xffffu));
        sm->hb_l[tid * 4 + 1] = bflo((unsigned)((q >> 16) & 0xffffu));
        sm->hb_l[tid * 4 + 2] = bflo((unsigned)((q >> 32) & 0xffffu));
        sm->hb_l[tid * 4 + 3] = bflo((unsigned)((q >> 48) & 0xffffu));
    }
    __syncthreads();

    // query: 2 threads per output col, each covers K=256
    {
        const int c  = tid >> 1;
        const int jj = tid & 1;
        const unsigned short* wr = Wqb + (long)c * HFS + jj * 256;
        const float* xr = &sm->hb_l[jj * 256];
        float qa = 0.0f;
#pragma unroll 8
        for (int k = 0; k < 256; k += 8) {
            uint4 u = *(const uint4*)(wr + k);
            float4 h0 = *(const float4*)(xr + k);
            float4 h1 = *(const float4*)(xr + k + 4);
            qa += bflo(u.x) * h0.x + bfhi(u.x) * h0.y
                + bflo(u.y) * h0.z + bfhi(u.y) * h0.w
                + bflo(u.z) * h1.x + bfhi(u.z) * h1.y
                + bflo(u.w) * h1.z + bfhi(u.w) * h1.w;
        }
        qa += __shfl_xor(qa, 1);
        if (jj == 0) sm->q_lds[c] = qa + bq[c];
    }
    __syncthreads();

    // energy: 8 threads per row (32 contiguous channels each), 64 rows per pass
    {
        const int jj   = tid & 7;
        const int rloc = tid >> 3;      // 0..63
        for (int r0 = 0; r0 < nv; r0 += 64) {
            const int r = r0 + rloc;
            float acc = 0.0f;
            if (r < nv) {
                if (KVBF) {
                    const unsigned short* kp = (const unsigned short*)keyp
                        + ((long)b * RAL + rbase + r) * CS + jj * 32;
#pragma unroll
                    for (int i = 0; i < 4; ++i) {
                        uint4 u = *(const uint4*)(kp + i * 8);
                        const float* qp = &sm->q_lds[jj * 32 + i * 8];
                        float4 qa  = *(const float4*)qp;
                        float4 qb2 = *(const float4*)(qp + 4);
                        acc += bflo(u.x) * qa.x  + bfhi(u.x) * qa.y
                             + bflo(u.y) * qa.z  + bfhi(u.y) * qa.w
                             + bflo(u.z) * qb2.x + bfhi(u.z) * qb2.y
                             + bflo(u.w) * qb2.z + bfhi(u.w) * qb2.w;
                    }
                } else {
                    const float* kp = (const float*)keyp
                        + ((long)b * RAL + rbase + r) * CS + jj * 32;
#pragma unroll
                    for (int i = 0; i < 8; ++i) {
                        float4 kv = *(const float4*)(kp + i * 4);
                        float4 qa = *(const float4*)&sm->q_lds[jj * 32 + i * 4];
                        acc += kv.x * qa.x + kv.y * qa.y + kv.z * qa.z + kv.w * qa.w;
                    }
                }
            }
            acc += __shfl_xor(acc, 1);
            acc += __shfl_xor(acc, 2);
            acc += __shfl_xor(acc, 4);
            if (jj == 0 && r < nv) sm->e_lds[r] = acc;
        }
    }
    __syncthreads();

    // local softmax stats (nv <= 512, one row per thread)
    float pm = (tid < nv) ? sm->e_lds[tid] : -1e30f;
#pragma unroll
    for (int s = 32; s > 0; s >>= 1) pm = fmaxf(pm, __shfl_xor(pm, s));
    if ((tid & 63) == 0) sm->red[tid >> 6] = pm;
    __syncthreads();
    float M = sm->red[0];
#pragma unroll
    for (int i = 1; i < 8; ++i) M = fmaxf(M, sm->red[i]);

    float ps = 0.0f;
    if (tid < nv) { float v = __expf(sm->e_lds[tid] - M); sm->e_lds[tid] = v; ps = v; }
#pragma unroll
    for (int s = 32; s > 0; s >>= 1) ps += __shfl_xor(ps, s);
    if ((tid & 63) == 0) sm->red[8 + (tid >> 6)] = ps;
    __syncthreads();
    float S = 0.0f;
#pragma unroll
    for (int i = 0; i < 8; ++i) S += sm->red[8 + i];

    if (tid == 0) {
        stu32(attM + b * NSPLIT + sp, fcb(M));
        stu32(attS + b * NSPLIT + sp, fcb(S));
    }

    // partial context (unnormalized): 8 waves, rows == wv (mod 8), lane owns 4 channels
    {
        const int wv = tid >> 6;
        const int c4 = (tid & 63) * 4;
        float a0 = 0.f, a1 = 0.f, a2 = 0.f, a3 = 0.f;
        if (KVBF) {
            const unsigned short* vb = (const unsigned short*)valp
                + ((long)b * RAL + rbase) * CS + c4;
            int r = wv;
            for (; r + 24 < nv; r += 32) {
                uint2 u0 = *(const uint2*)(vb + (long)(r)      * CS);
                uint2 u1 = *(const uint2*)(vb + (long)(r + 8)  * CS);
                uint2 u2 = *(const uint2*)(vb + (long)(r + 16) * CS);
                uint2 u3 = *(const uint2*)(vb + (long)(r + 24) * CS);
                float w0 = sm->e_lds[r],      w1 = sm->e_lds[r + 8];
                float w2 = sm->e_lds[r + 16], w3 = sm->e_lds[r + 24];
                a0 += w0 * bflo(u0.x) + w1 * bflo(u1.x) + w2 * bflo(u2.x) + w3 * bflo(u3.x);
                a1 += w0 * bfhi(u0.x) + w1 * bfhi(u1.x) + w2 * bfhi(u2.x) + w3 * bfhi(u3.x);
                a2 += w0 * bflo(u0.y) + w1 * bflo(u1.y) + w2 * bflo(u2.y) + w3 * bflo(u3.y);
                a3 += w0 * bfhi(u0.y) + w1 * bfhi(u1.y) + w2 * bfhi(u2.y) + w3 * bfhi(u3.y);
            }
            for (; r < nv; r += 8) {
                uint2 u = *(const uint2*)(vb + (long)r * CS);
                float w = sm->e_lds[r];
                a0 += w * bflo(u.x); a1 += w * bfhi(u.x);
                a2 += w * bflo(u.y); a3 += w * bfhi(u.y);
            }
        } else {
            const float* vb = (const float*)valp + ((long)b * RAL + rbase) * CS + c4;
            int r = wv;
            for (; r + 24 < nv; r += 32) {
                float4 v0 = *(const float4*)(vb + (long)(r)      * CS);
                float4 v1 = *(const float4*)(vb + (long)(r + 8)  * CS);
                float4 v2 = *(const float4*)(vb + (long)(r + 16) * CS);
                float4 v3 = *(const float4*)(vb + (long)(r + 24) * CS);
                float w0 = sm->e_lds[r],      w1 = sm->e_lds[r + 8];
                float w2 = sm->e_lds[r + 16], w3 = sm->e_lds[r + 24];
                a0 += w0 * v0.x + w1 * v1.x + w2 * v2.x + w3 * v3.x;
                a1 += w0 * v0.y + w1 * v1.y + w2 * v2.y + w3 * v3.y;
                a2 += w0 * v0.z + w1 * v1.z + w2 * v2.z + w3 * v3.z;
                a3 += w0 * v0.w + w1 * v1.w + w2 * v2.w + w3 * v3.w;
            }
            for (; r < nv; r += 8) {
                float4 v = *(const float4*)(vb + (long)r * CS);
                float w = sm->e_lds[r];
                a0 += w * v.x; a1 += w * v.y; a2 += w * v.z; a3 += w * v.w;
            }
        }
        float4 out4 = {a0, a1, a2, a3};
        *(float4*)&sm->ctxp[tid >> 6][c4] = out4;
    }
    __syncthreads();

    if (tid < CS) {
        float cv = 0.0f;
#pragma unroll
        for (int w = 0; w < 8; ++w) cv += sm->ctxp[w][tid];
        stu32(attC + ((long)b * NSPLIT + sp) * CS + tid, fcb(cv));   // unnormalized
    }
}

// ---------------- logits: each block does a (16-batch, 1-2 vocab) slice ----------------
static __device__ __forceinline__ void logits_phase(
    int blk, int tid,
    const unsigned short* __restrict__ hb,
    const float* __restrict__ attM, const float* __restrict__ attS,
    const float* __restrict__ attC,
    const float* __restrict__ Wc, const float* __restrict__ bc,
    float* __restrict__ outp, int tOut)
{
    const int bgr  = blk >> 5;        // 0..7
    const int vsl  = blk & 31;        // 0..31
    const int bloc = tid >> 5;        // 0..15
    const int jj   = tid & 31;        // 0..31
    const int b    = bgr * 16 + bloc;

    float M0 = bcf(ldu32(attM + b * 2)),     M1 = bcf(ldu32(attM + b * 2 + 1));
    float S0 = bcf(ldu32(attS + b * 2)),     S1 = bcf(ldu32(attS + b * 2 + 1));
    float mm = fmaxf(M0, M1);
    float w0 = __expf(M0 - mm), w1 = __expf(M1 - mm);
    float inv = 1.0f / (w0 * S0 + w1 * S1);
    w0 *= inv; w1 *= inv;

    float xh[16];
    const unsigned short* hp = hb + (long)b * HFS + jj * 16;
#pragma unroll
    for (int g = 0; g < 4; ++g) {
        unsigned long long q = ldu64(hp + g * 4);
        xh[g * 4 + 0] = bflo((unsigned)( q        & 0xffffu));
        xh[g * 4 + 1] = bflo((unsigned)((q >> 16) & 0xffffu));
        xh[g * 4 + 2] = bflo((unsigned)((q >> 32) & 0xffffu));
        xh[g * 4 + 3] = bflo((unsigned)((q >> 48) & 0xffffu));
    }
    float xc[8];
    const float* c0 = attC + ((long)b * NSPLIT + 0) * CS + jj * 8;
    const float* c1 = attC + ((long)b * NSPLIT + 1) * CS + jj * 8;
#pragma unroll
    for (int g = 0; g < 4; ++g) {
        unsigned long long qa = ldu64(c0 + g * 2);
        unsigned long long qb = ldu64(c1 + g * 2);
        xc[g * 2 + 0] = w0 * bcf((unsigned)qa)         + w1 * bcf((unsigned)qb);
        xc[g * 2 + 1] = w0 * bcf((unsigned)(qa >> 32)) + w1 * bcf((unsigned)(qb >> 32));
    }

#pragma unroll
    for (int vv = 0; vv < 2; ++vv) {
        int v = vsl + vv * 32;
        if (v >= VOC) break;
        const float* wr = Wc + (long)v * (HFS + CS);
        float part = 0.0f;
#pragma unroll
        for (int g = 0; g < 4; ++g) {
            float4 wv4 = *(const float4*)(wr + jj * 16 + g * 4);
            part += wv4.x * xh[g * 4 + 0] + wv4.y * xh[g * 4 + 1]
                  + wv4.z * xh[g * 4 + 2] + wv4.w * xh[g * 4 + 3];
        }
#pragma unroll
        for (int g = 0; g < 2; ++g) {
            float4 wv4 = *(const float4*)(wr + HFS + jj * 8 + g * 4);
            part += wv4.x * xc[g * 4 + 0] + wv4.y * xc[g * 4 + 1]
                  + wv4.z * xc[g * 4 + 2] + wv4.w * xc[g * 4 + 3];
        }
        part += __shfl_xor(part, 1);
        part += __shfl_xor(part, 2);
        part += __shfl_xor(part, 4);
        part += __shfl_xor(part, 8);
        part += __shfl_xor(part, 16);
        if (jj == 0)
            outp[((long)b * LAL + tOut) * VOC + v] = part + bc[v];
    }
}

// ---------------- fused kernel: all timesteps, custom barrier ----------------
template <bool KVBF>
__global__ __launch_bounds__(512) void fused_kernel(PParams P)
{
    __shared__ __align__(16) unsigned char smraw[SMSZ];
    SmLstm* smL = (SmLstm*)smraw;
    SmAttn* smA = (SmAttn*)smraw;

    const int blk = blockIdx.x;
    const int tid = threadIdx.x;
    int round = 0;

    for (int t = 0; t < LAL; ++t) {
        const unsigned short* haIn  = P.ha   + (t & 1) * (BS * HFS);
        unsigned short*       haOut = P.ha   + ((t + 1) & 1) * (BS * HFS);
        const unsigned short* hbIn  = P.hbuf + (t & 1) * (BS * HFS);
        unsigned short*       hbOut = P.hbuf + ((t + 1) & 1) * (BS * HFS);

        // phase 1: LSTM A (x = [emb | merged ctx], h = haIn)
        lstm_phase<true>(blk, tid, nullptr, P.attM, P.attS, P.attC,
                         P.embb, P.y, t, haIn,
                         P.WihA, P.WhhA, P.bihA, P.bhhA, P.ca, haOut, smL);
        gbar(P.grp, P.root, blk, round++);

        // phase 2: logits(t-1) + LSTM B (x = haOut, h = hbIn)
        if (t > 0)
            logits_phase(blk, tid, hbIn, P.attM, P.attS, P.attC, P.Wc, P.bc, P.outp, t - 1);
        lstm_phase<false>(blk, tid, haOut, nullptr, nullptr, nullptr,
                          nullptr, nullptr, t, hbIn,
                          P.WihB, P.WhhB, P.bihB, P.bhhB, P.cbuf, hbOut, smL);
        gbar(P.grp, P.root, blk, round++);

        // phase 3: attention partials
        attn_phase<KVBF>(blk, tid, P.keyp, P.valp, P.Llen, hbOut,
                         P.Wqb, P.bq, P.attM, P.attS, P.attC, smA);
        gbar(P.grp, P.root, blk, round++);
    }
    // final logits (t = LAL-1); hb(LAL-1) lives in hbuf[LAL & 1] == hbuf[0]
    logits_phase(blk, tid, P.hbuf + (LAL & 1) * (BS * HFS),
                 P.attM, P.attS, P.attC, P.Wc, P.bc, P.outp, LAL - 1);
}

// ---------------- host ----------------
extern "C" void kernel_launch(void* const* d_in, const int* in_sizes, int n_in,
                              void* d_out, int out_size, void* d_ws, size_t ws_size,
                              hipStream_t stream)
{
    (void)in_sizes; (void)n_in; (void)out_size;
    const float* keyf  = (const float*)d_in[0];
    const float* valf  = (const float*)d_in[1];
    const float* mask  = (const float*)d_in[2];
    const float* embf  = (const float*)d_in[3];
    const float* WihAf = (const float*)d_in[4];
    const float* WhhAf = (const float*)d_in[5];
    const float* bihA  = (const float*)d_in[6];
    const float* bhhA  = (const float*)d_in[7];
    const float* WihBf = (const float*)d_in[8];
    const float* WhhBf = (const float*)d_in[9];
    const float* bihB  = (const float*)d_in[10];
    const float* bhhB  = (const float*)d_in[11];
    const float* Wqf   = (const float*)d_in[12];
    const float* bq    = (const float*)d_in[13];
    const float* Wc    = (const float*)d_in[14];
    const float* bc    = (const float*)d_in[15];
    const int*   y     = (const int*)d_in[16];
    float* outp = (float*)d_out;

    size_t off = 0;
    auto take = [&](size_t bytes) -> void* {
        void* p = (char*)d_ws + off;
        off += (bytes + 255) & ~(size_t)255;
        return p;
    };

    // ---- zero-initialized state block (memset every launch) ----
    unsigned short* ha    = (unsigned short*)take((size_t)2 * BS * HFS * 2); // double-buffered
    unsigned short* hbuf  = (unsigned short*)take((size_t)2 * BS * HFS * 2); // double-buffered
    float*          ca    = (float*)take((size_t)BS * HFS * 4);
    float*          cbuf  = (float*)take((size_t)BS * HFS * 4);
    float*          attM  = (float*)take((size_t)BS * NSPLIT * 4);
    float*          attS  = (float*)take((size_t)BS * NSPLIT * 4);
    float*          attC  = (float*)take((size_t)BS * NSPLIT * CS * 4);
    unsigned*       grp   = (unsigned*)take((size_t)16 * 32 * 4);   // padded group counters
    unsigned*       root  = (unsigned*)take((size_t)32 * 4);
    size_t stateBytes = off;

    int*            Llen  = (int*)take((size_t)BS * 4);
    unsigned short* embb  = (unsigned short*)take((size_t)VOC * EMB * 2);
    unsigned short* WihAb = (unsigned short*)take((size_t)4 * HFS * HFS * 2);
    unsigned short* WhhAb = (unsigned short*)take((size_t)4 * HFS * HFS * 2);
    unsigned short* WihBb = (unsigned short*)take((size_t)4 * HFS * HFS * 2);
    unsigned short* WhhBb = (unsigned short*)take((size_t)4 * HFS * HFS * 2);
    unsigned short* Wqb   = (unsigned short*)take((size_t)CS * HFS * 2);

    // --- KV bf16 tiers ---
    const size_t kvBytes = (size_t)BS * RAL * CS * 2;  // 67 MB each
    unsigned short* keyb = nullptr;
    unsigned short* valb = nullptr;
    bool kvbf = false;
    bool keyInVal = false;
    if (off + 2 * (kvBytes + 256) <= ws_size) {
        keyb = (unsigned short*)take(kvBytes);
        valb = (unsigned short*)take(kvBytes);
        kvbf = true;
    } else if (off + kvBytes + 256 <= ws_size) {
        valb = (unsigned short*)take(kvBytes);
        keyb = (unsigned short*)d_in[1];
        kvbf = true;
        keyInVal = true;
    }

    hipMemsetAsync(d_ws, 0, stateBytes, stream);
    len_kernel<<<dim3(BS), dim3(256), 0, stream>>>(mask, Llen, attS);

    auto cvt = [&](const float* src, unsigned short* dst, long n) {
        int n4 = (int)(n / 4);
        int blocks = (n4 + 255) / 256;
        if (blocks > 8192) blocks = 8192;
        cvt4_kernel<<<dim3(blocks), dim3(256), 0, stream>>>((const float4*)src, (ushort4*)dst, n4);
    };
    cvt(embf,  embb,  (long)VOC * EMB);
    cvt(WihAf, WihAb, (long)4 * HFS * HFS);
    cvt(WhhAf, WhhAb, (long)4 * HFS * HFS);
    cvt(WihBf, WihBb, (long)4 * HFS * HFS);
    cvt(WhhBf, WhhBb, (long)4 * HFS * HFS);
    cvt(Wqf,   Wqb,   (long)CS * HFS);
    if (kvbf) {
        if (keyInVal) {
            cvt(valf, valb, (long)BS * RAL * CS);   // must finish before key overwrites d_in[1]
            cvt(keyf, keyb, (long)BS * RAL * CS);
        } else {
            cvt(keyf, keyb, (long)BS * RAL * CS);
            cvt(valf, valb, (long)BS * RAL * CS);
        }
    }

    PParams prm;
    prm.keyp = kvbf ? (const void*)keyb : (const void*)keyf;
    prm.valp = kvbf ? (const void*)valb : (const void*)valf;
    prm.Llen = Llen; prm.y = y;
    prm.embb = embb;
    prm.WihA = WihAb; prm.WhhA = WhhAb; prm.bihA = bihA; prm.bhhA = bhhA;
    prm.WihB = WihBb; prm.WhhB = WhhBb; prm.bihB = bihB; prm.bhhB = bhhB;
    prm.Wqb = Wqb; prm.bq = bq; prm.Wc = Wc; prm.bc = bc;
    prm.ha = ha; prm.hbuf = hbuf; prm.ca = ca; prm.cbuf = cbuf;
    prm.attM = attM; prm.attS = attS; prm.attC = attC;
    prm.grp = grp; prm.root = root;
    prm.outp = outp;

    void* kargs[] = { &prm };
    if (kvbf)
        hipLaunchCooperativeKernel(reinterpret_cast<void*>(&fused_kernel<true>),
                                   dim3(NBLK), dim3(512), kargs, 0, stream);
    else
        hipLaunchCooperativeKernel(reinterpret_cast<void*>(&fused_kernel<false>),
                                   dim3(NBLK), dim3(512), kargs, 0, stream);
}